// Round 1
// baseline (1592.601 us; speedup 1.0000x reference)
//
#include <hip/hip_runtime.h>
#include <hip/hip_bf16.h>

// Problem constants
constexpr int B  = 2;
constexpr int N  = 2048;
constexpr int D  = 1024;
constexpr int H  = 16;
constexpr int Dh = 64;
constexpr int C  = 256;
constexpr int CD = 512;
constexpr int J  = C + 1 + N;   // 2305
constexpr float EPS = 1e-5f;
constexpr float NEG_MAX = -3.402823466e38f;

// ---------------------------------------------------------------------------
// Kernel 0: mask dtype sniff + unpack to int32 (1 = keep).
// The reference mask is bool (B, C+N). The harness contract says integer ->
// int*, but bool could plausibly arrive as u8 or f32. Detect by scanning the
// first 1152 words (safe to read in all three interpretations).
__global__ void mask_prep(const void* __restrict__ mraw, int* __restrict__ smask) {
    __shared__ int bad_int, bad_f32;
    const int t = threadIdx.x;
    if (t == 0) { bad_int = 0; bad_f32 = 0; }
    __syncthreads();
    const unsigned int* w = (const unsigned int*)mraw;
    int li = 0, lf = 0;
    for (int i = t; i < 1152; i += 256) {
        unsigned int v = w[i];
        if (v > 1u) li = 1;
        if (v != 0u && v != 0x3F800000u) lf = 1;
    }
    if (li) atomicOr(&bad_int, 1);
    if (lf) atomicOr(&bad_f32, 1);
    __syncthreads();
    // mode 0: int32 0/1; mode 1: f32 0.0/1.0; mode 2: u8 per element
    const int mode = (!bad_int) ? 0 : ((!bad_f32) ? 1 : 2);
    const int total = B * (C + N);   // 4608
    const unsigned char* bytes = (const unsigned char*)mraw;
    for (int i = t; i < total; i += 256) {
        int v;
        if (mode == 2) v = (bytes[i] != 0);
        else           v = (w[i] != 0u);   // covers both int32 0/1 and f32 bits
        smask[i] = v;
    }
}

// ---------------------------------------------------------------------------
// Kernel 1: layernorm over last dim = 1024 (beta = 0). One block per row.
__global__ void __launch_bounds__(256) ln1024(const float* __restrict__ x,
                                              const float* __restrict__ gamma,
                                              float* __restrict__ out) {
    const int row = blockIdx.x;
    const int t = threadIdx.x;
    const float* xr = x + (size_t)row * 1024;
    float4 v = ((const float4*)xr)[t];
    float s  = v.x + v.y + v.z + v.w;
    float ss = v.x * v.x + v.y * v.y + v.z * v.z + v.w * v.w;
    #pragma unroll
    for (int o = 1; o < 64; o <<= 1) {
        s  += __shfl_xor(s, o);
        ss += __shfl_xor(ss, o);
    }
    __shared__ float red[8];
    const int w = t >> 6;
    if ((t & 63) == 0) { red[w * 2] = s; red[w * 2 + 1] = ss; }
    __syncthreads();
    s  = red[0] + red[2] + red[4] + red[6];
    ss = red[1] + red[3] + red[5] + red[7];
    const float mean = s * (1.0f / 1024.0f);
    const float var  = ss * (1.0f / 1024.0f) - mean * mean;
    const float rstd = rsqrtf(var + EPS);
    const float4 g = ((const float4*)gamma)[t];
    float4 o4;
    o4.x = (v.x - mean) * rstd * g.x;
    o4.y = (v.y - mean) * rstd * g.y;
    o4.z = (v.z - mean) * rstd * g.z;
    o4.w = (v.w - mean) * rstd * g.w;
    ((float4*)(out + (size_t)row * 1024))[t] = o4;
}

// ---------------------------------------------------------------------------
// Kernel 2: context path: layernorm(context row, CD=512) @ Wctx + bctx
// -> ck into Kb rows [0,256), cv into Vb rows [0,256). One block (128 thr)/row.
__global__ void __launch_bounds__(128) ctx_proj(const float* __restrict__ ctx,
                                                const float* __restrict__ lw,
                                                const float* __restrict__ lb,
                                                const float* __restrict__ Wc,
                                                const float* __restrict__ bc,
                                                float* __restrict__ Kb,
                                                float* __restrict__ Vb) {
    const int row = blockIdx.x;          // 0..511
    const int b = row >> 8, ci = row & 255;
    const int t = threadIdx.x;           // 0..127
    __shared__ float cn[512];
    const float* xr = ctx + (size_t)row * 512;
    float4 v = ((const float4*)xr)[t];
    float s  = v.x + v.y + v.z + v.w;
    float ss = v.x * v.x + v.y * v.y + v.z * v.z + v.w * v.w;
    #pragma unroll
    for (int o = 1; o < 64; o <<= 1) {
        s  += __shfl_xor(s, o);
        ss += __shfl_xor(ss, o);
    }
    __shared__ float red[4];
    const int w = t >> 6;
    if ((t & 63) == 0) { red[w * 2] = s; red[w * 2 + 1] = ss; }
    __syncthreads();
    s  = red[0] + red[2];
    ss = red[1] + red[3];
    const float mean = s * (1.0f / 512.0f);
    const float var  = ss * (1.0f / 512.0f) - mean * mean;
    const float rstd = rsqrtf(var + EPS);
    const float4 g  = ((const float4*)lw)[t];
    const float4 be = ((const float4*)lb)[t];
    float4 c4;
    c4.x = (v.x - mean) * rstd * g.x + be.x;
    c4.y = (v.y - mean) * rstd * g.y + be.y;
    c4.z = (v.z - mean) * rstd * g.z + be.z;
    c4.w = (v.w - mean) * rstd * g.w + be.w;
    *(float4*)&cn[t * 4] = c4;
    __syncthreads();
    // output column t of (ck|cv)
    float acc = bc[t];
    #pragma unroll 8
    for (int d = 0; d < 512; d++) acc += cn[d] * Wc[d * 128 + t];
    if (t < 64) Kb[((size_t)b * J + ci) * 64 + t] = acc;
    else        Vb[((size_t)b * J + ci) * 64 + (t - 64)] = acc;
}

// ---------------------------------------------------------------------------
// Kernel 3: null kv token -> row 256 of Kb/Vb.
__global__ void null_fill(const float* __restrict__ nkv,
                          float* __restrict__ Kb, float* __restrict__ Vb) {
    const int b = blockIdx.x;
    const int t = threadIdx.x;   // 0..63
    Kb[((size_t)b * J + 256) * 64 + t] = nkv[t];
    Vb[((size_t)b * J + 256) * 64 + t] = nkv[64 + t];
}

// ---------------------------------------------------------------------------
// Kernel 4: f32 GEMM, 128x128 tile, BK=8, 256 threads, 8x8 microtile.
// A (M,K) row-major, Bm (K,Nn) row-major.
// MODE 0: Cp[r*1024 + col] = acc * scale
// MODE 1: kv scatter: col<64 -> Kb row 257+token, else Vb (Nn==128, ldc n/a)
template <int MODE>
__global__ void __launch_bounds__(256) gemm128(const float* __restrict__ A,
                                               const float* __restrict__ Bm,
                                               float* __restrict__ Cp,
                                               float* __restrict__ Kb,
                                               float* __restrict__ Vb,
                                               int K, int ldb, float scale) {
    __shared__ __align__(16) float As[8][132];   // [k][m] (transposed)
    __shared__ __align__(16) float Bs[8][132];   // [k][n]
    const int row0 = blockIdx.x * 128, col0 = blockIdx.y * 128;
    const int t = threadIdx.x;
    const int tr = t >> 4, tc = t & 15;
    float acc[8][8] = {};
    const int am = t >> 1, ak = (t & 1) * 4;
    const int bk = t >> 5, bn = (t & 31) * 4;
    const float* Aptr = A + (size_t)(row0 + am) * K + ak;
    const float* Bptr = Bm + (size_t)bk * ldb + col0 + bn;
    for (int k0 = 0; k0 < K; k0 += 8) {
        const float4 a4 = *(const float4*)(Aptr + k0);
        const float4 b4 = *(const float4*)(Bptr + (size_t)k0 * ldb);
        As[ak + 0][am] = a4.x;
        As[ak + 1][am] = a4.y;
        As[ak + 2][am] = a4.z;
        As[ak + 3][am] = a4.w;
        *(float4*)&Bs[bk][bn] = b4;
        __syncthreads();
        #pragma unroll
        for (int k = 0; k < 8; k++) {
            const float4 alo = *(const float4*)&As[k][tr * 8];
            const float4 ahi = *(const float4*)&As[k][tr * 8 + 4];
            const float4 blo = *(const float4*)&Bs[k][tc * 8];
            const float4 bhi = *(const float4*)&Bs[k][tc * 8 + 4];
            const float av[8] = {alo.x, alo.y, alo.z, alo.w, ahi.x, ahi.y, ahi.z, ahi.w};
            const float bv[8] = {blo.x, blo.y, blo.z, blo.w, bhi.x, bhi.y, bhi.z, bhi.w};
            #pragma unroll
            for (int i = 0; i < 8; i++)
                #pragma unroll
                for (int j = 0; j < 8; j++)
                    acc[i][j] = fmaf(av[i], bv[j], acc[i][j]);
        }
        __syncthreads();
    }
    if (MODE == 0) {
        #pragma unroll
        for (int i = 0; i < 8; i++) {
            const int r = row0 + tr * 8 + i;
            float* cr = Cp + (size_t)r * 1024 + col0 + tc * 8;
            float4 lo = make_float4(acc[i][0] * scale, acc[i][1] * scale,
                                    acc[i][2] * scale, acc[i][3] * scale);
            float4 hi = make_float4(acc[i][4] * scale, acc[i][5] * scale,
                                    acc[i][6] * scale, acc[i][7] * scale);
            *(float4*)cr = lo;
            *(float4*)(cr + 4) = hi;
        }
    } else {
        #pragma unroll
        for (int i = 0; i < 8; i++) {
            const int r = row0 + tr * 8 + i;
            const int b = r >> 11, ti = r & 2047;
            const int n = col0 + tc * 8;   // 0..120, no 64-boundary straddle
            float* dst = (n < 64) ? (Kb + ((size_t)b * J + 257 + ti) * 64 + n)
                                  : (Vb + ((size_t)b * J + 257 + ti) * 64 + (n - 64));
            float4 lo = make_float4(acc[i][0], acc[i][1], acc[i][2], acc[i][3]);
            float4 hi = make_float4(acc[i][4], acc[i][5], acc[i][6], acc[i][7]);
            *(float4*)dst = lo;
            *(float4*)(dst + 4) = hi;
        }
    }
}

// ---------------------------------------------------------------------------
// Kernel 5: flash attention. Block = 256 threads, 64 q-rows, j-tile = 64.
// Thread (gi = t/8, sub = t%8) owns rows r0=2*gi, r1=2*gi+1 and cols sub*8..+7.
// q pre-scaled by Dh^-0.5. bias (H,N,J) added; mask: j==0 always kept,
// else smask[b][j-1] (replicates reference's left-pad-True quirk).
__global__ void __launch_bounds__(256) attn_fwd(const float* __restrict__ q,
                                                const float* __restrict__ Kb,
                                                const float* __restrict__ Vb,
                                                const float* __restrict__ bias,
                                                const int* __restrict__ smask,
                                                float* __restrict__ outp) {
    __shared__ __align__(16) float q_s[64][68];   // [r][d]
    __shared__ __align__(16) float k_s[64][68];   // transposed: [d][c]
    __shared__ __align__(16) float v_s[64][68];   // [c][d]
    __shared__ float p_s[64][66];                 // [c][r]
    __shared__ int msk_s[64];
    const int bx = blockIdx.x;    // i-tile 0..31
    const int h  = blockIdx.y;    // 0..15
    const int b  = blockIdx.z;    // 0..1
    const int i0 = bx * 64;
    const int t = threadIdx.x;
    const int sub = t & 7;
    const int gi  = t >> 3;
    const int r0 = gi * 2, r1 = r0 + 1;

    // load q tile (64 rows x 64)
    #pragma unroll
    for (int rep = 0; rep < 4; rep++) {
        const int idx = t + rep * 256;
        const int r = idx >> 4, f4i = idx & 15;
        const float4 v = *(const float4*)(q + ((size_t)(b * N + i0 + r)) * 1024 + h * 64 + f4i * 4);
        *(float4*)&q_s[r][f4i * 4] = v;
    }

    float m0 = NEG_MAX, m1 = NEG_MAX, l0 = 0.f, l1 = 0.f;
    float o0[8] = {}, o1[8] = {};
    const float* biasH = bias + (size_t)h * N * J;

    for (int j0 = 0; j0 < J; j0 += 64) {
        // stage K (transposed) and V tiles
        #pragma unroll
        for (int rep = 0; rep < 4; rep++) {
            const int idx = t + rep * 256;
            const int c = idx >> 4, f4i = idx & 15;
            const int j = j0 + c;
            float4 k4 = make_float4(0.f, 0.f, 0.f, 0.f);
            float4 v4 = make_float4(0.f, 0.f, 0.f, 0.f);
            if (j < J) {
                k4 = *(const float4*)(Kb + ((size_t)b * J + j) * 64 + f4i * 4);
                v4 = *(const float4*)(Vb + ((size_t)b * J + j) * 64 + f4i * 4);
            }
            const int d = f4i * 4;
            k_s[d + 0][c] = k4.x;
            k_s[d + 1][c] = k4.y;
            k_s[d + 2][c] = k4.z;
            k_s[d + 3][c] = k4.w;
            *(float4*)&v_s[c][d] = v4;
        }
        if (t < 64) {
            const int j = j0 + t;
            msk_s[t] = (j == 0) ? 1 : ((j < J) ? smask[b * (C + N) + j - 1] : 0);
        }
        __syncthreads();

        // S = q . k^T for 2 rows x 8 cols
        float s0[8] = {}, s1[8] = {};
        #pragma unroll 8
        for (int d = 0; d < 64; d++) {
            const float q0 = q_s[r0][d];
            const float q1 = q_s[r1][d];
            const float4 klo = *(const float4*)&k_s[d][sub * 8];
            const float4 khi = *(const float4*)&k_s[d][sub * 8 + 4];
            const float kv[8] = {klo.x, klo.y, klo.z, klo.w, khi.x, khi.y, khi.z, khi.w};
            #pragma unroll
            for (int cc = 0; cc < 8; cc++) {
                s0[cc] = fmaf(q0, kv[cc], s0[cc]);
                s1[cc] = fmaf(q1, kv[cc], s1[cc]);
            }
        }
        // bias + mask, tile max
        float tmax0 = NEG_MAX, tmax1 = NEG_MAX;
        const float* br0 = biasH + (size_t)(i0 + r0) * J + j0;
        const float* br1 = biasH + (size_t)(i0 + r1) * J + j0;
        #pragma unroll
        for (int cc = 0; cc < 8; cc++) {
            const int c = sub * 8 + cc;
            const int mk = msk_s[c];
            s0[cc] = mk ? (s0[cc] + br0[c]) : NEG_MAX;
            s1[cc] = mk ? (s1[cc] + br1[c]) : NEG_MAX;
            tmax0 = fmaxf(tmax0, s0[cc]);
            tmax1 = fmaxf(tmax1, s1[cc]);
        }
        #pragma unroll
        for (int o = 1; o < 8; o <<= 1) {
            tmax0 = fmaxf(tmax0, __shfl_xor(tmax0, o));
            tmax1 = fmaxf(tmax1, __shfl_xor(tmax1, o));
        }
        const float mn0 = fmaxf(m0, tmax0);
        const float mn1 = fmaxf(m1, tmax1);
        const float cor0 = __expf(m0 - mn0);
        const float cor1 = __expf(m1 - mn1);
        float ts0 = 0.f, ts1 = 0.f;
        #pragma unroll
        for (int cc = 0; cc < 8; cc++) {
            const int c = sub * 8 + cc;
            const float p0 = __expf(s0[cc] - mn0);
            const float p1 = __expf(s1[cc] - mn1);
            ts0 += p0;
            ts1 += p1;
            p_s[c][r0] = p0;
            p_s[c][r1] = p1;
        }
        #pragma unroll
        for (int o = 1; o < 8; o <<= 1) {
            ts0 += __shfl_xor(ts0, o);
            ts1 += __shfl_xor(ts1, o);
        }
        l0 = l0 * cor0 + ts0;
        l1 = l1 * cor1 + ts1;
        #pragma unroll
        for (int cc = 0; cc < 8; cc++) { o0[cc] *= cor0; o1[cc] *= cor1; }
        m0 = mn0;
        m1 = mn1;
        __syncthreads();   // p_s visible (conservative; also orders vs k_s reads)

        // PV: o += P @ V
        #pragma unroll 8
        for (int j = 0; j < 64; j++) {
            const float pa = p_s[j][r0];
            const float pb = p_s[j][r1];
            const float4 vlo = *(const float4*)&v_s[j][sub * 8];
            const float4 vhi = *(const float4*)&v_s[j][sub * 8 + 4];
            const float vv[8] = {vlo.x, vlo.y, vlo.z, vlo.w, vhi.x, vhi.y, vhi.z, vhi.w};
            #pragma unroll
            for (int cc = 0; cc < 8; cc++) {
                o0[cc] = fmaf(pa, vv[cc], o0[cc]);
                o1[cc] = fmaf(pb, vv[cc], o1[cc]);
            }
        }
        __syncthreads();   // before next tile overwrites k_s/v_s/p_s
    }

    const float inv0 = 1.0f / l0;
    const float inv1 = 1.0f / l1;
    float* orow0 = outp + ((size_t)(b * N + i0 + r0)) * 1024 + h * 64 + sub * 8;
    float* orow1 = outp + ((size_t)(b * N + i0 + r1)) * 1024 + h * 64 + sub * 8;
    *(float4*)orow0       = make_float4(o0[0] * inv0, o0[1] * inv0, o0[2] * inv0, o0[3] * inv0);
    *(float4*)(orow0 + 4) = make_float4(o0[4] * inv0, o0[5] * inv0, o0[6] * inv0, o0[7] * inv0);
    *(float4*)orow1       = make_float4(o1[0] * inv1, o1[1] * inv1, o1[2] * inv1, o1[3] * inv1);
    *(float4*)(orow1 + 4) = make_float4(o1[4] * inv1, o1[5] * inv1, o1[6] * inv1, o1[7] * inv1);
}

// ---------------------------------------------------------------------------
extern "C" void kernel_launch(void* const* d_in, const int* in_sizes, int n_in,
                              void* d_out, int out_size, void* d_ws, size_t ws_size,
                              hipStream_t stream) {
    const float* x         = (const float*)d_in[0];
    const float* context   = (const float*)d_in[1];
    const void*  mask      = d_in[2];
    const float* bias      = (const float*)d_in[3];
    const float* norm_g    = (const float*)d_in[4];
    const float* null_kv   = (const float*)d_in[5];
    const float* Wq        = (const float*)d_in[6];
    const float* Wkv       = (const float*)d_in[7];
    const float* ctx_ln_w  = (const float*)d_in[8];
    const float* ctx_ln_b  = (const float*)d_in[9];
    const float* Wctx      = (const float*)d_in[10];
    const float* bctx      = (const float*)d_in[11];
    const float* Wout      = (const float*)d_in[12];
    const float* out_gamma = (const float*)d_in[13];
    float* out = (float*)d_out;

    float* ws = (float*)d_ws;
    float* xn = ws;                         // 4194304 f
    float* qb = ws + 4194304;               // 4194304 f
    float* Kb = ws + 8388608;               // 295040 f
    float* Vb = ws + 8683648;               // 295040 f
    int* smask = (int*)(ws + 8978688);      // 4608 i
    float* attn_out = xn;                   // reuse (xn dead after projections)
    float* y = qb;                          // reuse (q dead after attention)

    mask_prep<<<1, 256, 0, stream>>>(mask, smask);
    ln1024<<<B * N, 256, 0, stream>>>(x, norm_g, xn);
    ctx_proj<<<B * C, 128, 0, stream>>>(context, ctx_ln_w, ctx_ln_b, Wctx, bctx, Kb, Vb);
    null_fill<<<B, 64, 0, stream>>>(null_kv, Kb, Vb);
    // q = xn @ Wq * Dh^-0.5  (M=4096, N=1024, K=1024)
    gemm128<0><<<dim3(32, 8), 256, 0, stream>>>(xn, Wq, qb, nullptr, nullptr, 1024, 1024, 0.125f);
    // k,v = xn @ Wkv -> scatter to Kb/Vb rows 257..  (M=4096, N=128, K=1024)
    gemm128<1><<<dim3(32, 1), 256, 0, stream>>>(xn, Wkv, nullptr, Kb, Vb, 1024, 128, 1.0f);
    attn_fwd<<<dim3(32, 16, 2), 256, 0, stream>>>(qb, Kb, Vb, bias, smask, attn_out);
    // y = attn_out @ Wout  (M=4096, N=1024, K=1024)
    gemm128<0><<<dim3(32, 8), 256, 0, stream>>>(attn_out, Wout, y, nullptr, nullptr, 1024, 1024, 1.0f);
    ln1024<<<B * N, 256, 0, stream>>>(y, out_gamma, out);
}

// Round 2
// 274.382 us; speedup vs baseline: 5.8043x; 5.8043x over previous
//
#include <hip/hip_runtime.h>

// Problem constants
constexpr int B  = 2;
constexpr int N  = 2048;
constexpr int H  = 16;
constexpr int C  = 256;
constexpr int J  = C + 1 + N;    // 2305
constexpr int Jp = 2368;         // J padded to multiple of 64
constexpr int NT = Jp / 64;      // 37 j-tiles
constexpr float EPS = 1e-5f;

typedef __bf16 bf16x8 __attribute__((ext_vector_type(8)));
typedef float  f32x4  __attribute__((ext_vector_type(4)));
typedef unsigned int uint4v __attribute__((ext_vector_type(4)));
typedef __attribute__((address_space(3))) unsigned int lds_u32;
typedef const __attribute__((address_space(1))) unsigned int glb_u32;

__device__ inline void load_lds16(const void* g, void* l) {
    __builtin_amdgcn_global_load_lds((glb_u32*)g, (lds_u32*)l, 16, 0, 0);
}
__device__ inline unsigned short f2bf(float f) {
    unsigned int u = __builtin_bit_cast(unsigned int, f);
    u += 0x7fffu + ((u >> 16) & 1u);
    return (unsigned short)(u >> 16);
}
__device__ inline unsigned int packbf(float a, float b) {
    return (unsigned int)f2bf(a) | ((unsigned int)f2bf(b) << 16);
}
__device__ inline f32x4 mfma16(bf16x8 a, bf16x8 b, f32x4 c) {
    return __builtin_amdgcn_mfma_f32_16x16x32_bf16(a, b, c, 0, 0, 0);
}

// ---------------------------------------------------------------------------
// Kernel 0: mask sniff + build additive mask maskf[b][Jp] (0 keep / -1e30 drop).
// Reference pads one True at j=0; pad region j>=J is -1e30 (masks tail tile).
__global__ void mask_prep(const void* __restrict__ mraw, float* __restrict__ maskf) {
    __shared__ int bad_int, bad_f32;
    const int t = threadIdx.x;
    if (t == 0) { bad_int = 0; bad_f32 = 0; }
    __syncthreads();
    const unsigned int* w = (const unsigned int*)mraw;
    int li = 0, lf = 0;
    for (int i = t; i < 1152; i += 256) {
        unsigned int v = w[i];
        if (v > 1u) li = 1;
        if (v != 0u && v != 0x3F800000u) lf = 1;
    }
    if (li) atomicOr(&bad_int, 1);
    if (lf) atomicOr(&bad_f32, 1);
    __syncthreads();
    const int mode = (!bad_int) ? 0 : ((!bad_f32) ? 1 : 2);
    const unsigned char* bytes = (const unsigned char*)mraw;
    for (int i = t; i < 2 * Jp; i += 256) {
        const int b2 = i / Jp, jp = i - b2 * Jp;
        float v;
        if (jp == 0) v = 0.f;
        else if (jp >= J) v = -1e30f;
        else {
            const int idx = b2 * (C + N) + jp - 1;
            const int keep = (mode == 2) ? (bytes[idx] != 0) : (w[idx] != 0u);
            v = keep ? 0.f : -1e30f;
        }
        maskf[i] = v;
    }
}

// ---------------------------------------------------------------------------
// Kernel 1: zero the pad region of Kb (rows J..Jp) and Vt (cols J..Jp).
__global__ void zero_pads(unsigned short* __restrict__ Kb, unsigned short* __restrict__ Vt) {
    const int t = threadIdx.x;
    for (int i = t; i < 2 * 63 * 64; i += 256) {
        const int b2 = i / (63 * 64);
        const int rr = (i / 64) % 63;
        const int d  = i % 64;
        Kb[(size_t)(b2 * Jp + J + rr) * 64 + d] = 0;
    }
    for (int i = t; i < 2 * 64 * 63; i += 256) {
        const int b2 = i / (64 * 63);
        const int d  = (i / 63) % 64;
        const int cc = i % 63;
        Vt[(size_t)(b2 * 64 + d) * Jp + J + cc] = 0;
    }
}

// ---------------------------------------------------------------------------
// Kernel 2: layernorm over 1024 (beta=0). BF16OUT: write bf16, else f32.
template <int BF16OUT>
__global__ void __launch_bounds__(256) ln1024(const float* __restrict__ x,
                                              const float* __restrict__ gamma,
                                              void* __restrict__ outp) {
    const int row = blockIdx.x;
    const int t = threadIdx.x;
    const float* xr = x + (size_t)row * 1024;
    float4 v = ((const float4*)xr)[t];
    float s  = v.x + v.y + v.z + v.w;
    float ss = v.x * v.x + v.y * v.y + v.z * v.z + v.w * v.w;
    #pragma unroll
    for (int o = 1; o < 64; o <<= 1) {
        s  += __shfl_xor(s, o);
        ss += __shfl_xor(ss, o);
    }
    __shared__ float red[8];
    const int w = t >> 6;
    if ((t & 63) == 0) { red[w * 2] = s; red[w * 2 + 1] = ss; }
    __syncthreads();
    s  = red[0] + red[2] + red[4] + red[6];
    ss = red[1] + red[3] + red[5] + red[7];
    const float mean = s * (1.0f / 1024.0f);
    const float var  = ss * (1.0f / 1024.0f) - mean * mean;
    const float rstd = rsqrtf(var + EPS);
    const float4 g = ((const float4*)gamma)[t];
    float o0 = (v.x - mean) * rstd * g.x;
    float o1 = (v.y - mean) * rstd * g.y;
    float o2 = (v.z - mean) * rstd * g.z;
    float o3 = (v.w - mean) * rstd * g.w;
    if (BF16OUT) {
        ushort4 u;
        u.x = f2bf(o0); u.y = f2bf(o1); u.z = f2bf(o2); u.w = f2bf(o3);
        *(ushort4*)((unsigned short*)outp + (size_t)row * 1024 + t * 4) = u;
    } else {
        *(float4*)((float*)outp + (size_t)row * 1024 + t * 4) = make_float4(o0, o1, o2, o3);
    }
}

// ---------------------------------------------------------------------------
// Kernel 3: transpose + bf16-convert a weight W(K x Nn) -> WT(Nn x K), *scale.
__global__ void __launch_bounds__(256) transpose_w(const float* __restrict__ W,
                                                   unsigned short* __restrict__ WT,
                                                   int K, int Nn, float scale) {
    __shared__ float lds[64][68];
    const int k0 = blockIdx.x * 64, n0 = blockIdx.y * 64;
    const int t = threadIdx.x;
    const int kk = t >> 4, nn = (t & 15) * 4;
    #pragma unroll
    for (int r = 0; r < 4; r++) {
        const float4 v = *(const float4*)(W + (size_t)(k0 + kk + r * 16) * Nn + n0 + nn);
        lds[kk + r * 16][nn + 0] = v.x;
        lds[kk + r * 16][nn + 1] = v.y;
        lds[kk + r * 16][nn + 2] = v.z;
        lds[kk + r * 16][nn + 3] = v.w;
    }
    __syncthreads();
    const int nr = t >> 2, kc = (t & 3) * 16;
    #pragma unroll
    for (int u4 = 0; u4 < 4; u4++) {
        ushort4 u;
        u.x = f2bf(lds[kc + u4 * 4 + 0][nr] * scale);
        u.y = f2bf(lds[kc + u4 * 4 + 1][nr] * scale);
        u.z = f2bf(lds[kc + u4 * 4 + 2][nr] * scale);
        u.w = f2bf(lds[kc + u4 * 4 + 3][nr] * scale);
        *(ushort4*)(WT + (size_t)(n0 + nr) * K + k0 + kc + u4 * 4) = u;
    }
}

// ---------------------------------------------------------------------------
// Kernel 4: context path: LN(context,512) @ Wctx + bctx -> Kb[0..255] / Vt cols.
__global__ void __launch_bounds__(128) ctx_proj(const float* __restrict__ ctx,
                                                const float* __restrict__ lw,
                                                const float* __restrict__ lb,
                                                const float* __restrict__ Wc,
                                                const float* __restrict__ bc,
                                                unsigned short* __restrict__ Kb,
                                                unsigned short* __restrict__ Vt) {
    const int row = blockIdx.x;          // 0..511
    const int b2 = row >> 8, ci = row & 255;
    const int t = threadIdx.x;           // 0..127
    __shared__ float cn[512];
    __shared__ float red[4];
    const float* xr = ctx + (size_t)row * 512;
    float4 v = ((const float4*)xr)[t];
    float s  = v.x + v.y + v.z + v.w;
    float ss = v.x * v.x + v.y * v.y + v.z * v.z + v.w * v.w;
    #pragma unroll
    for (int o = 1; o < 64; o <<= 1) {
        s  += __shfl_xor(s, o);
        ss += __shfl_xor(ss, o);
    }
    const int w = t >> 6;
    if ((t & 63) == 0) { red[w * 2] = s; red[w * 2 + 1] = ss; }
    __syncthreads();
    s  = red[0] + red[2];
    ss = red[1] + red[3];
    const float mean = s * (1.0f / 512.0f);
    const float var  = ss * (1.0f / 512.0f) - mean * mean;
    const float rstd = rsqrtf(var + EPS);
    const float4 g  = ((const float4*)lw)[t];
    const float4 be = ((const float4*)lb)[t];
    float4 c4;
    c4.x = (v.x - mean) * rstd * g.x + be.x;
    c4.y = (v.y - mean) * rstd * g.y + be.y;
    c4.z = (v.z - mean) * rstd * g.z + be.z;
    c4.w = (v.w - mean) * rstd * g.w + be.w;
    *(float4*)&cn[t * 4] = c4;
    __syncthreads();
    float acc = bc[t];
    #pragma unroll 8
    for (int d = 0; d < 512; d++) acc = fmaf(cn[d], Wc[d * 128 + t], acc);
    const unsigned short bv = f2bf(acc);
    if (t < 64) Kb[(size_t)(b2 * Jp + ci) * 64 + t] = bv;
    else        Vt[(size_t)(b2 * 64 + (t - 64)) * Jp + ci] = bv;
}

// ---------------------------------------------------------------------------
// Kernel 5: null token -> Kb row 256 / Vt col 256.
__global__ void null_fill(const float* __restrict__ nkv,
                          unsigned short* __restrict__ Kb, unsigned short* __restrict__ Vt) {
    const int b2 = blockIdx.x;
    const int t = threadIdx.x;   // 0..63
    Kb[(size_t)(b2 * Jp + 256) * 64 + t] = f2bf(nkv[t]);
    Vt[(size_t)(b2 * 64 + t) * Jp + 256] = f2bf(nkv[64 + t]);
}

// ---------------------------------------------------------------------------
// Kernel 6: bf16 MFMA GEMM, 128x128 tile, BK=64, 4 waves, 2-phase dbuf.
// A (M,K) bf16 row-major; BT (Nn,K) bf16 row-major (= B^T).
// MODE 0: Cf f32 [M,Nn].  MODE 1: Cb bf16 [M,Nn].  MODE 2: kv scatter.
template <int MODE>
__global__ void __launch_bounds__(256, 2) gemm_bf16(
        const unsigned short* __restrict__ A, const unsigned short* __restrict__ BT,
        float* __restrict__ Cf, unsigned short* __restrict__ Cb,
        unsigned short* __restrict__ Kb, unsigned short* __restrict__ Vt,
        int M, int Nn, int K) {
    __shared__ __align__(16) unsigned char smem[65536];
    const int t = threadIdx.x;
    const int w = t >> 6, lane = t & 63;
    const int g = lane >> 4, ln15 = lane & 15;
    const int wm = w >> 1, wn = w & 1;
    const int row0 = blockIdx.x * 128, col0 = blockIdx.y * 128;
    const int nk = K >> 6;
    const int ls = lane >> 3;
    const int swz = (lane & 7) ^ ls;

    f32x4 acc[4][4];
    #pragma unroll
    for (int i = 0; i < 4; i++)
        #pragma unroll
        for (int jj = 0; jj < 4; jj++)
            acc[i][jj] = (f32x4){0.f, 0.f, 0.f, 0.f};

    // stage one K-tile (BK=64) into buffer cur
    auto stage = [&](int kt, int cur) {
        if (w < 2) {
            const unsigned short* src = A + (size_t)(row0 + w * 64 + ls) * K + kt * 64 + swz * 8;
            unsigned char* dst = smem + cur * 16384 + w * 8192;
            #pragma unroll
            for (int i = 0; i < 8; i++)
                load_lds16(src + (size_t)i * 8 * K, dst + i * 1024);
        } else {
            const unsigned short* src = BT + (size_t)(col0 + (w - 2) * 64 + ls) * K + kt * 64 + swz * 8;
            unsigned char* dst = smem + 32768 + cur * 16384 + (w - 2) * 8192;
            #pragma unroll
            for (int i = 0; i < 8; i++)
                load_lds16(src + (size_t)i * 8 * K, dst + i * 1024);
        }
    };

    stage(0, 0);
    __syncthreads();
    for (int kt = 0; kt < nk; kt++) {
        const int cur = kt & 1;
        if (kt + 1 < nk) stage(kt + 1, cur ^ 1);
        const unsigned char* As = smem + cur * 16384;
        const unsigned char* Bs = smem + 32768 + cur * 16384;
        #pragma unroll
        for (int ks = 0; ks < 2; ks++) {
            bf16x8 af[4], bf[4];
            #pragma unroll
            for (int mq = 0; mq < 4; mq++)
                af[mq] = *(const bf16x8*)(As + (wm * 64 + mq * 16 + ln15) * 128 +
                                          ((ks * 64 + g * 16) ^ ((ln15 & 7) << 4)));
            #pragma unroll
            for (int nq = 0; nq < 4; nq++)
                bf[nq] = *(const bf16x8*)(Bs + (wn * 64 + nq * 16 + ln15) * 128 +
                                          ((ks * 64 + g * 16) ^ ((ln15 & 7) << 4)));
            #pragma unroll
            for (int mq = 0; mq < 4; mq++)
                #pragma unroll
                for (int nq = 0; nq < 4; nq++)
                    acc[mq][nq] = mfma16(af[mq], bf[nq], acc[mq][nq]);
        }
        __syncthreads();
    }

    #pragma unroll
    for (int mq = 0; mq < 4; mq++) {
        #pragma unroll
        for (int nq = 0; nq < 4; nq++) {
            #pragma unroll
            for (int r = 0; r < 4; r++) {
                const int gr = row0 + wm * 64 + mq * 16 + g * 4 + r;
                const int gc = col0 + wn * 64 + nq * 16 + ln15;
                if (MODE == 0) {
                    Cf[(size_t)gr * Nn + gc] = acc[mq][nq][r];
                } else if (MODE == 1) {
                    Cb[(size_t)gr * Nn + gc] = f2bf(acc[mq][nq][r]);
                } else {
                    const int b2 = gr >> 11, tok = gr & 2047;
                    const unsigned short v = f2bf(acc[mq][nq][r]);
                    if (gc < 64) Kb[(size_t)(b2 * Jp + 257 + tok) * 64 + gc] = v;
                    else         Vt[(size_t)(b2 * 64 + gc - 64) * Jp + 257 + tok] = v;
                }
            }
        }
    }
}

// ---------------------------------------------------------------------------
// Kernel 7: flash attention, MFMA bf16, swapped QK^T.
// Grid (N/64, H). Block = 4 waves; wave owns 16 q-rows; both batches per
// block (bias loaded once, reused). K row-major [j][64], V transposed [d][Jp].
__global__ void __launch_bounds__(256, 2) attn_mfma(
        const unsigned short* __restrict__ qb, const unsigned short* __restrict__ Kb,
        const unsigned short* __restrict__ Vt, const float* __restrict__ bias,
        const float* __restrict__ maskf, unsigned short* __restrict__ aout) {
    __shared__ __align__(16) unsigned char smem[65536];
    const int t = threadIdx.x;
    const int w = t >> 6, lane = t & 63;
    const int g = lane >> 4, ln15 = lane & 15;
    const int i0 = blockIdx.x * 64, h = blockIdx.y;
    const int ls = lane >> 3;
    const int swz = (lane & 7) ^ ls;

    // stage K[b0],K[b1],Vt[b0],Vt[b1] (8KB each) for j-tile jt into buffer cur
    auto stage = [&](int jt, int cur) {
        const int j0 = jt * 64;
        const int b2 = w & 1;
        const unsigned short* src;
        size_t sstep;
        if (w < 2) { src = Kb + (size_t)(b2 * Jp + j0 + ls) * 64 + swz * 8; sstep = (size_t)8 * 64; }
        else       { src = Vt + (size_t)(b2 * 64 + ls) * Jp + j0 + swz * 8; sstep = (size_t)8 * Jp; }
        unsigned char* dst = smem + cur * 32768 + w * 8192;
        #pragma unroll
        for (int i = 0; i < 8; i++)
            load_lds16(src + i * sstep, dst + i * 1024);
    };

    // Q fragments (B-operand of swapped QK^T): q-row = ln15, d k-contig.
    bf16x8 qf[2][2];
    #pragma unroll
    for (int b2 = 0; b2 < 2; b2++)
        #pragma unroll
        for (int ks = 0; ks < 2; ks++)
            qf[b2][ks] = *(const bf16x8*)(qb + (size_t)(b2 * N + i0 + w * 16 + ln15) * 1024 +
                                          h * 64 + ks * 32 + g * 8);

    float mrun[2] = {-1e30f, -1e30f};
    float lrun[2] = {0.f, 0.f};
    f32x4 outA[2][4];
    #pragma unroll
    for (int b2 = 0; b2 < 2; b2++)
        #pragma unroll
        for (int nq = 0; nq < 4; nq++)
            outA[b2][nq] = (f32x4){0.f, 0.f, 0.f, 0.f};

    const float* biasRow = bias + ((size_t)h * N + (i0 + w * 16 + ln15)) * J;

    stage(0, 0);
    __syncthreads();

    for (int jt = 0; jt < NT; jt++) {
        const int cur = jt & 1;
        const int j0 = jt * 64;
        if (jt + 1 < NT) stage(jt + 1, cur ^ 1);

        // bias tile -> regs (shared by both batches); q-row = ln15, j per (jqm,g,rr)
        float br[4][4];
        if (jt < NT - 1) {
            #pragma unroll
            for (int jqm = 0; jqm < 4; jqm++)
                #pragma unroll
                for (int rr = 0; rr < 4; rr++)
                    br[jqm][rr] = biasRow[j0 + jqm * 16 + g * 4 + rr];
        } else {
            #pragma unroll
            for (int jqm = 0; jqm < 4; jqm++)
                #pragma unroll
                for (int rr = 0; rr < 4; rr++) {
                    const int jj = j0 + jqm * 16 + g * 4 + rr;
                    br[jqm][rr] = (jj < J) ? biasRow[jj] : 0.f;
                }
        }

        #pragma unroll
        for (int b2 = 0; b2 < 2; b2++) {
            const unsigned char* Kl = smem + cur * 32768 + b2 * 8192;
            const unsigned char* Vl = smem + cur * 32768 + 16384 + b2 * 8192;

            f32x4 mk[4];
            #pragma unroll
            for (int jqm = 0; jqm < 4; jqm++)
                mk[jqm] = *(const f32x4*)(maskf + b2 * Jp + j0 + jqm * 16 + g * 4);

            // S^T = K . Q : frag jqm rows j = j0+jqm*16+g*4+r, col q = ln15
            f32x4 S[4];
            #pragma unroll
            for (int jqm = 0; jqm < 4; jqm++) S[jqm] = (f32x4){0.f, 0.f, 0.f, 0.f};
            #pragma unroll
            for (int ks = 0; ks < 2; ks++) {
                bf16x8 ka[4];
                #pragma unroll
                for (int jqm = 0; jqm < 4; jqm++)
                    ka[jqm] = *(const bf16x8*)(Kl + (jqm * 16 + ln15) * 128 +
                                               ((ks * 64 + g * 16) ^ ((ln15 & 7) << 4)));
                #pragma unroll
                for (int jqm = 0; jqm < 4; jqm++)
                    S[jqm] = mfma16(ka[jqm], qf[b2][ks], S[jqm]);
            }

            float sv[4][4];
            #pragma unroll
            for (int jqm = 0; jqm < 4; jqm++)
                #pragma unroll
                for (int r = 0; r < 4; r++)
                    sv[jqm][r] = S[jqm][r] + br[jqm][r] + mk[jqm][r];

            // online softmax, row (q=ln15) spread over 4 lane-groups
            float tm = -1e30f;
            #pragma unroll
            for (int jqm = 0; jqm < 4; jqm++)
                #pragma unroll
                for (int r = 0; r < 4; r++)
                    tm = fmaxf(tm, sv[jqm][r]);
            tm = fmaxf(tm, __shfl_xor(tm, 16));
            tm = fmaxf(tm, __shfl_xor(tm, 32));
            const float mnew = fmaxf(mrun[b2], tm);
            const float cor = __expf(mrun[b2] - mnew);
            mrun[b2] = mnew;

            float p[4][4];
            float ts = 0.f;
            #pragma unroll
            for (int jqm = 0; jqm < 4; jqm++)
                #pragma unroll
                for (int r = 0; r < 4; r++) {
                    p[jqm][r] = __expf(sv[jqm][r] - mnew);
                    ts += p[jqm][r];
                }
            ts += __shfl_xor(ts, 16);
            ts += __shfl_xor(ts, 32);
            lrun[b2] = lrun[b2] * cor + ts;

            // rescale out accumulators (their q = g*4+r, cor lives at lane q)
            float corr[4];
            #pragma unroll
            for (int r = 0; r < 4; r++) corr[r] = __shfl(cor, g * 4 + r, 64);
            #pragma unroll
            for (int nq = 0; nq < 4; nq++)
                #pragma unroll
                for (int r = 0; r < 4; r++)
                    outA[b2][nq][r] *= corr[r];

            // pack P to bf16 pairs: W[jqm][0]=(r0,r1), W[jqm][1]=(r2,r3)
            unsigned int Wp[4][2];
            #pragma unroll
            for (int jqm = 0; jqm < 4; jqm++) {
                Wp[jqm][0] = packbf(p[jqm][0], p[jqm][1]);
                Wp[jqm][1] = packbf(p[jqm][2], p[jqm][3]);
            }

            // repack to PV A-fragments: lane needs P[q=ln15][j=ks*32+g*8+0..7]
            #pragma unroll
            for (int ks = 0; ks < 2; ks++) {
                uint4v wd;
                #pragma unroll
                for (int widx = 0; widx < 4; widx++) {
                    const int srcl = ln15 + (((2 * g + (widx >> 1)) & 3) << 4);
                    const int t0 = __shfl((int)Wp[ks * 2 + 0][widx & 1], srcl, 64);
                    const int t1 = __shfl((int)Wp[ks * 2 + 1][widx & 1], srcl, 64);
                    wd[widx] = (unsigned int)((g >> 1) ? t1 : t0);
                }
                const bf16x8 pa = __builtin_bit_cast(bf16x8, wd);
                #pragma unroll
                for (int nq = 0; nq < 4; nq++) {
                    const bf16x8 vf = *(const bf16x8*)(Vl + (nq * 16 + ln15) * 128 +
                                                       ((ks * 64 + g * 16) ^ ((ln15 & 7) << 4)));
                    outA[b2][nq] = mfma16(pa, vf, outA[b2][nq]);
                }
            }
        }
        __syncthreads();
    }

    #pragma unroll
    for (int b2 = 0; b2 < 2; b2++) {
        const float inv = 1.0f / lrun[b2];
        float invr[4];
        #pragma unroll
        for (int r = 0; r < 4; r++) invr[r] = __shfl(inv, g * 4 + r, 64);
        #pragma unroll
        for (int nq = 0; nq < 4; nq++)
            #pragma unroll
            for (int r = 0; r < 4; r++)
                aout[(size_t)(b2 * N + i0 + w * 16 + g * 4 + r) * 1024 +
                     h * 64 + nq * 16 + ln15] = f2bf(outA[b2][nq][r] * invr[r]);
    }
}

// ---------------------------------------------------------------------------
extern "C" void kernel_launch(void* const* d_in, const int* in_sizes, int n_in,
                              void* d_out, int out_size, void* d_ws, size_t ws_size,
                              hipStream_t stream) {
    const float* x         = (const float*)d_in[0];
    const float* context   = (const float*)d_in[1];
    const void*  mask      = d_in[2];
    const float* bias      = (const float*)d_in[3];
    const float* norm_g    = (const float*)d_in[4];
    const float* null_kv   = (const float*)d_in[5];
    const float* Wq        = (const float*)d_in[6];
    const float* Wkv       = (const float*)d_in[7];
    const float* ctx_ln_w  = (const float*)d_in[8];
    const float* ctx_ln_b  = (const float*)d_in[9];
    const float* Wctx      = (const float*)d_in[10];
    const float* bctx      = (const float*)d_in[11];
    const float* Wout      = (const float*)d_in[12];
    const float* out_gamma = (const float*)d_in[13];
    float* out = (float*)d_out;

    unsigned char* wsb = (unsigned char*)d_ws;
    unsigned short* xnb   = (unsigned short*)(wsb + 0);          //  8 MB bf16
    unsigned short* qbb   = (unsigned short*)(wsb + 8388608);    //  8 MB bf16
    float*          y     = (float*)(wsb + 0);                   // 16 MB f32 (overlays xnb+qbb, both dead)
    unsigned short* aoutp = (unsigned short*)(wsb + 16777216);   //  8 MB bf16
    unsigned short* KbP   = (unsigned short*)(wsb + 25165824);   // 2*Jp*64 bf16
    unsigned short* VtP   = (unsigned short*)(wsb + 25772032);   // 2*64*Jp bf16
    float*          maskf = (float*)(wsb + 26378240);            // 2*Jp f32
    unsigned short* WqT   = (unsigned short*)(wsb + 26397184);   // 2 MB
    unsigned short* WkvT  = (unsigned short*)(wsb + 28494336);   // 256 KB
    unsigned short* WoutT = (unsigned short*)(wsb + 28756480);   // 2 MB

    mask_prep<<<1, 256, 0, stream>>>(mask, maskf);
    zero_pads<<<1, 256, 0, stream>>>(KbP, VtP);
    ln1024<1><<<B * N, 256, 0, stream>>>(x, norm_g, xnb);
    transpose_w<<<dim3(16, 16), 256, 0, stream>>>(Wq, WqT, 1024, 1024, 0.125f);
    transpose_w<<<dim3(16, 2), 256, 0, stream>>>(Wkv, WkvT, 1024, 128, 1.0f);
    transpose_w<<<dim3(16, 16), 256, 0, stream>>>(Wout, WoutT, 1024, 1024, 1.0f);
    ctx_proj<<<B * C, 128, 0, stream>>>(context, ctx_ln_w, ctx_ln_b, Wctx, bctx, KbP, VtP);
    null_fill<<<B, 64, 0, stream>>>(null_kv, KbP, VtP);
    // q = LN(x) @ (Wq*0.125) -> bf16 (4096 x 1024)
    gemm_bf16<1><<<dim3(32, 8), 256, 0, stream>>>(xnb, WqT, nullptr, qbb, nullptr, nullptr, 4096, 1024, 1024);
    // k,v = LN(x) @ Wkv -> scatter bf16 into Kb rows / Vt cols 257..2304
    gemm_bf16<2><<<dim3(32, 1), 256, 0, stream>>>(xnb, WkvT, nullptr, nullptr, KbP, VtP, 4096, 128, 1024);
    attn_mfma<<<dim3(32, 16), 256, 0, stream>>>(qbb, KbP, VtP, bias, maskf, aoutp);
    // y = attn_out @ Wout -> f32
    gemm_bf16<0><<<dim3(32, 8), 256, 0, stream>>>(aoutp, WoutT, y, nullptr, nullptr, nullptr, 4096, 1024, 1024);
    ln1024<0><<<B * N, 256, 0, stream>>>(y, out_gamma, out);
}